// Round 2
// baseline (151.739 us; speedup 1.0000x reference)
//
#include <hip/hip_runtime.h>
#include <hip/hip_bf16.h>
#include <cstdint>
#include <cstddef>

#define B_ 8
#define C_ 256
#define N_ 2048
#define H_ 32
#define VP_ 2064            // vbf padded row stride (elems) = 4128 B
#define NT_ (N_ / 64)

typedef __bf16 bf8 __attribute__((ext_vector_type(8)));
typedef __bf16 bf4 __attribute__((ext_vector_type(4)));
typedef float f4 __attribute__((ext_vector_type(4)));
typedef float f16v __attribute__((ext_vector_type(16)));

__device__ inline void gload_lds16(const void* g, void* l) {
  __builtin_amdgcn_global_load_lds(
      (const __attribute__((address_space(1))) unsigned int*)g,
      (__attribute__((address_space(3))) unsigned int*)l, 16, 0, 0);
}

// ---- P1: pack weights: wpk bf16 [320][256] = {wv; wq; wk}, bpk fp32 [320] ----
// wq/bq pre-scaled by log2(e): fused kernel then uses raw v_exp_f32 (exp2).
__global__ __launch_bounds__(256) void pack_kernel(
    const float* __restrict__ wq, const float* __restrict__ wk,
    const float* __restrict__ wv, const float* __restrict__ bq,
    const float* __restrict__ bk, const float* __restrict__ bv,
    __hip_bfloat16* __restrict__ wpk, float* __restrict__ bpk) {
  const float L2E = 1.44269504088896f;
  int r = blockIdx.x, c = threadIdx.x;
  float v;
  if (r < 256)      v = wv[r * 256 + c];
  else if (r < 288) v = wq[(r - 256) * 256 + c] * L2E;
  else              v = wk[(r - 288) * 256 + c];
  wpk[r * 256 + c] = __float2bfloat16(v);
  if (c == 0) bpk[r] = (r < 256) ? bv[r] : (r < 288 ? bq[r - 256] * L2E : bk[r - 288]);
}

// ---- P2: proj GEMM (unchanged; vbf stride VP_) ----
__global__ __launch_bounds__(256) void proj_kernel(
    const float* __restrict__ x, const __hip_bfloat16* __restrict__ wpk,
    const float* __restrict__ bpk, __hip_bfloat16* __restrict__ vbf,
    __hip_bfloat16* __restrict__ qkb) {
  __shared__ __attribute__((aligned(16))) __hip_bfloat16 As[2][320 * 32];  // 40 KB
  int tid = threadIdx.x, wv = tid >> 6, lane = tid & 63;
  int b = blockIdx.y;
  int n0 = blockIdx.x * 32;
  int fcol = lane & 15, hi4 = lane >> 4;
  int grow = lane >> 2, gc = (lane & 3) * 8;
  const float* xb = x + (size_t)b * C_ * N_;

#pragma unroll
  for (int g = 0; g < 5; ++g)
    gload_lds16(wpk + (size_t)(wv * 80 + g * 16 + grow) * 256 + gc,
                &As[0][(wv * 80 + g * 16) * 32]);
  float xr[2][8];
#pragma unroll
  for (int j = 0; j < 2; ++j)
#pragma unroll
    for (int e = 0; e < 8; ++e)
      xr[j][e] = xb[(size_t)(hi4 * 8 + e) * N_ + n0 + j * 16 + fcol];

  f4 acc[5][2] = {};
  for (int t = 0; t < 8; ++t) {
    int buf = t & 1;
    __syncthreads();
    if (t < 7) {
      int k1 = (t + 1) * 32;
#pragma unroll
      for (int g = 0; g < 5; ++g)
        gload_lds16(wpk + (size_t)(wv * 80 + g * 16 + grow) * 256 + k1 + gc,
                    &As[buf ^ 1][(wv * 80 + g * 16) * 32]);
    }
    bf8 bfr[2];
#pragma unroll
    for (int j = 0; j < 2; ++j)
#pragma unroll
      for (int e = 0; e < 8; ++e) bfr[j][e] = (__bf16)xr[j][e];
    if (t < 7) {
      int k1 = (t + 1) * 32;
#pragma unroll
      for (int j = 0; j < 2; ++j)
#pragma unroll
        for (int e = 0; e < 8; ++e)
          xr[j][e] = xb[(size_t)(k1 + hi4 * 8 + e) * N_ + n0 + j * 16 + fcol];
    }
#pragma unroll
    for (int s = 0; s < 5; ++s) {
      bf8 af = *(const bf8*)&As[buf][(wv * 80 + s * 16 + fcol) * 32 + hi4 * 8];
      acc[s][0] = __builtin_amdgcn_mfma_f32_16x16x32_bf16(af, bfr[0], acc[s][0], 0, 0, 0);
      acc[s][1] = __builtin_amdgcn_mfma_f32_16x16x32_bf16(af, bfr[1], acc[s][1], 0, 0, 0);
    }
  }
  int rq = hi4 * 4;
#pragma unroll
  for (int s = 0; s < 5; ++s)
#pragma unroll
    for (int r = 0; r < 4; ++r) {
      int m = wv * 80 + s * 16 + rq + r;
      float bias = bpk[m];
#pragma unroll
      for (int j = 0; j < 2; ++j) {
        int n = n0 + j * 16 + fcol;
        float val = acc[s][j][r] + bias;
        if (m < 256)
          vbf[((size_t)b * C_ + m) * VP_ + n] = __float2bfloat16(val);
        else
          qkb[((size_t)b * N_ + n) * 64 + (m - 256)] = __float2bfloat16(val);
      }
    }
}

// ---- fused attention v6: 1024 blocks (4/CU, 16 waves/CU), 4-wave quadrant
// blocks over (c-slice 64, i-slice 64). Per wave/iter: 2 S-MFMA + 16 exp2 +
// 4 PV-MFMA. Copy-free 2-deep reg pipeline (unroll x2, two named reg sets);
// raw s_barrier with lgkm-only drain; K/V prefetch stays in flight across it.
#define ATTN_BODY(T, BUF, CK0, CK1, CV0, CV1, CV2, CV3,                        \
                  NK0, NK1, NV0, NV1, NV2, NV3)                                \
  {                                                                            \
    int tn_ = (T) + 1 < NT_ ? (T) + 1 : (T);                                   \
    const __hip_bfloat16* kpn_ = kp + (size_t)tn_ * 64 * 64;                   \
    NK0 = *(const bf8*)kpn_;                                                   \
    NK1 = *(const bf8*)(kpn_ + 16);                                            \
    const __hip_bfloat16* vpn_ = vR + tn_ * 64;                                \
    NV0 = *(const bf8*)vpn_;                                                   \
    NV1 = *(const bf8*)(vpn_ + 16);                                            \
    NV2 = *(const bf8*)(vpn_ + 32);                                            \
    NV3 = *(const bf8*)(vpn_ + 48);                                            \
    f16v s = {};                                                               \
    s = __builtin_amdgcn_mfma_f32_32x32x16_bf16(CK0, qf0, s, 0, 0, 0);         \
    s = __builtin_amdgcn_mfma_f32_32x32x16_bf16(CK1, qf1, s, 0, 0, 0);         \
    _Pragma("unroll")                                                          \
    for (int r = 0; r < 16; ++r) s[r] = __builtin_amdgcn_exp2f(s[r]);          \
    _Pragma("unroll")                                                          \
    for (int r = 0; r < 16; r += 2) { lp0 += s[r]; lp1 += s[r + 1]; }          \
    __hip_bfloat16* pw_ = &pS[BUF][iw * 32 + l31][jw * 32 + 4 * hi];           \
    _Pragma("unroll")                                                          \
    for (int q = 0; q < 4; ++q) {                                              \
      bf4 tb_;                                                                 \
      tb_[0] = (__bf16)s[4 * q + 0];                                           \
      tb_[1] = (__bf16)s[4 * q + 1];                                           \
      tb_[2] = (__bf16)s[4 * q + 2];                                           \
      tb_[3] = (__bf16)s[4 * q + 3];                                           \
      *(bf4*)(pw_ + 8 * q) = tb_;                                              \
    }                                                                          \
    asm volatile("s_waitcnt lgkmcnt(0)" ::: "memory");                         \
    __builtin_amdgcn_s_barrier();                                              \
    const __hip_bfloat16* pr_ = &pS[BUF][iw * 32 + l31][hi * 8];               \
    __builtin_amdgcn_s_setprio(1);                                             \
    {                                                                          \
      bf8 pf0_ = *(const bf8*)(pr_ + 0);                                       \
      acc = __builtin_amdgcn_mfma_f32_32x32x16_bf16(CV0, pf0_, acc, 0, 0, 0);  \
      bf8 pf1_ = *(const bf8*)(pr_ + 16);                                      \
      acc = __builtin_amdgcn_mfma_f32_32x32x16_bf16(CV1, pf1_, acc, 0, 0, 0);  \
      bf8 pf2_ = *(const bf8*)(pr_ + 32);                                      \
      acc = __builtin_amdgcn_mfma_f32_32x32x16_bf16(CV2, pf2_, acc, 0, 0, 0);  \
      bf8 pf3_ = *(const bf8*)(pr_ + 48);                                      \
      acc = __builtin_amdgcn_mfma_f32_32x32x16_bf16(CV3, pf3_, acc, 0, 0, 0);  \
    }                                                                          \
    __builtin_amdgcn_s_setprio(0);                                             \
  }

__global__ __launch_bounds__(256, 4) void fused_attn(
    const __hip_bfloat16* __restrict__ qk,   // [b][n][64]: q 0..31, k 32..63
    const __hip_bfloat16* __restrict__ vbf,  // [b][c][VP_]
    const float* __restrict__ x, float* __restrict__ out) {
  __shared__ __attribute__((aligned(16))) __hip_bfloat16 pS[2][64][88];  // 22 KB
  __shared__ float lSp[2][64];
  int tid = threadIdx.x;
  int w = tid >> 6, lane = tid & 63;
  int l31 = lane & 31, hi = lane >> 5;
  int jw = w & 1, iw = w >> 1;
  // XCD-pinning: b = blk&7 pins batch b's 128 blocks to one XCD's L2.
  int blk = blockIdx.x;
  int b = blk & 7;
  int rest = blk >> 3;        // 0..127
  int cs = rest & 3;          // c-slice of 64
  int i0 = (rest >> 2) * 64;  // i-slice of 64

  const __hip_bfloat16* qkB = qk + (size_t)b * N_ * 64;
  // Q frag (B of S^T): col i = i0 + iw*32 + l31, k = h
  const __hip_bfloat16* qp = qkB + (size_t)(i0 + iw * 32 + l31) * 64 + hi * 8;
  bf8 qf0 = *(const bf8*)qp;
  bf8 qf1 = *(const bf8*)(qp + 16);
  // K frag (A of S^T): row j = t*64 + jw*32 + l31, k = h
  const __hip_bfloat16* kp = qkB + (size_t)(jw * 32 + l31) * 64 + 32 + hi * 8;
  // V frag (A of PV): row c = cs*64 + jw*32 + l31, k = j-local
  const __hip_bfloat16* vR =
      vbf + ((size_t)b * C_ + cs * 64 + jw * 32 + l31) * VP_ + hi * 8;

  bf8 kA0 = *(const bf8*)kp;
  bf8 kA1 = *(const bf8*)(kp + 16);
  bf8 vA0 = *(const bf8*)vR;
  bf8 vA1 = *(const bf8*)(vR + 16);
  bf8 vA2 = *(const bf8*)(vR + 32);
  bf8 vA3 = *(const bf8*)(vR + 48);
  bf8 kB0, kB1, vB0, vB1, vB2, vB3;

  f16v acc = {};
  float lp0 = 0.f, lp1 = 0.f;

  for (int tt = 0; tt < NT_; tt += 2) {
    ATTN_BODY(tt, 0, kA0, kA1, vA0, vA1, vA2, vA3,
              kB0, kB1, vB0, vB1, vB2, vB3)
    ATTN_BODY(tt + 1, 1, kB0, kB1, vB0, vB1, vB2, vB3,
              kA0, kA1, vA0, vA1, vA2, vA3)
  }

  // softmax denominator: lane-local (per i-col) partial over own (jw,hi) rows;
  // combine hi-halves via shfl, jw-halves via LDS.
  float lp = lp0 + lp1;
  lp += __shfl_xor(lp, 32);
  if (lane < 32) lSp[jw][iw * 32 + l31] = lp;
  __syncthreads();
  float linv = 1.0f / (lSp[0][iw * 32 + l31] + lSp[1][iw * 32 + l31]);

  const float* xr = x + (size_t)b * C_ * N_;
  float* op = out + (size_t)b * C_ * N_;
  int i = i0 + iw * 32 + l31;
#pragma unroll
  for (int r = 0; r < 16; ++r) {
    int crow = (r & 3) + 8 * (r >> 2) + 4 * hi;
    size_t o = (size_t)(cs * 64 + jw * 32 + crow) * N_ + i;
    op[o] = acc[r] * linv + xr[o];
  }
}

extern "C" void kernel_launch(void* const* d_in, const int* in_sizes, int n_in,
                              void* d_out, int out_size, void* d_ws, size_t ws_size,
                              hipStream_t stream) {
  const float* x  = (const float*)d_in[0];
  const float* wq = (const float*)d_in[1];
  const float* bq = (const float*)d_in[2];
  const float* wk = (const float*)d_in[3];
  const float* bk = (const float*)d_in[4];
  const float* wv = (const float*)d_in[5];
  const float* bv = (const float*)d_in[6];
  float* out = (float*)d_out;

  char* ws = (char*)d_ws;
  __hip_bfloat16* qkb = (__hip_bfloat16*)ws;                        // 2 MiB [b][n][64]
  __hip_bfloat16* vbf = (__hip_bfloat16*)(ws + (2u << 20));         // 8.06 MiB [b][c][VP_]
  __hip_bfloat16* wpk = (__hip_bfloat16*)(ws + 10551296u);          // 160 KiB [320][256]
  float*          bpk = (float*)(ws + 10551296u + 163840u);

  pack_kernel<<<dim3(320), 256, 0, stream>>>(wq, wk, wv, bq, bk, bv, wpk, bpk);
  proj_kernel<<<dim3(N_ / 32, B_), 256, 0, stream>>>(x, wpk, bpk, vbf, qkb);
  fused_attn<<<dim3(1024), 256, 0, stream>>>(qkb, vbf, x, out);
}

// Round 4
// 128.187 us; speedup vs baseline: 1.1837x; 1.1837x over previous
//
#include <hip/hip_runtime.h>
#include <hip/hip_bf16.h>
#include <cstdint>
#include <cstddef>

#define B_ 8
#define C_ 256
#define N_ 2048
#define H_ 32
#define VP_ 2064            // vbf padded row stride (elems) = 4128 B
#define NT_ (N_ / 64)

typedef __bf16 bf8 __attribute__((ext_vector_type(8)));
typedef __bf16 bf4 __attribute__((ext_vector_type(4)));
typedef float f4 __attribute__((ext_vector_type(4)));
typedef float f16v __attribute__((ext_vector_type(16)));

__device__ inline void gload_lds16(const void* g, void* l) {
  __builtin_amdgcn_global_load_lds(
      (const __attribute__((address_space(1))) unsigned int*)g,
      (__attribute__((address_space(3))) unsigned int*)l, 16, 0, 0);
}

// ---- P1: pack weights: wpk bf16 [320][256] = {wv; wq; wk}, bpk fp32 [320] ----
// wq/bq pre-scaled by log2(e): fused kernel uses raw v_exp_f32 (exp2).
__global__ __launch_bounds__(256) void pack_kernel(
    const float* __restrict__ wq, const float* __restrict__ wk,
    const float* __restrict__ wv, const float* __restrict__ bq,
    const float* __restrict__ bk, const float* __restrict__ bv,
    __hip_bfloat16* __restrict__ wpk, float* __restrict__ bpk) {
  const float L2E = 1.44269504088896f;
  int r = blockIdx.x, c = threadIdx.x;
  float v;
  if (r < 256)      v = wv[r * 256 + c];
  else if (r < 288) v = wq[(r - 256) * 256 + c] * L2E;
  else              v = wk[(r - 288) * 256 + c];
  wpk[r * 256 + c] = __float2bfloat16(v);
  if (c == 0) bpk[r] = (r < 256) ? bv[r] : (r < 288 ? bq[r - 256] * L2E : bk[r - 288]);
}

// ---- P2: proj GEMM (unchanged; vbf stride VP_) ----
__global__ __launch_bounds__(256) void proj_kernel(
    const float* __restrict__ x, const __hip_bfloat16* __restrict__ wpk,
    const float* __restrict__ bpk, __hip_bfloat16* __restrict__ vbf,
    __hip_bfloat16* __restrict__ qkb) {
  __shared__ __attribute__((aligned(16))) __hip_bfloat16 As[2][320 * 32];  // 40 KB
  int tid = threadIdx.x, wv = tid >> 6, lane = tid & 63;
  int b = blockIdx.y;
  int n0 = blockIdx.x * 32;
  int fcol = lane & 15, hi4 = lane >> 4;
  int grow = lane >> 2, gc = (lane & 3) * 8;
  const float* xb = x + (size_t)b * C_ * N_;

#pragma unroll
  for (int g = 0; g < 5; ++g)
    gload_lds16(wpk + (size_t)(wv * 80 + g * 16 + grow) * 256 + gc,
                &As[0][(wv * 80 + g * 16) * 32]);
  float xr[2][8];
#pragma unroll
  for (int j = 0; j < 2; ++j)
#pragma unroll
    for (int e = 0; e < 8; ++e)
      xr[j][e] = xb[(size_t)(hi4 * 8 + e) * N_ + n0 + j * 16 + fcol];

  f4 acc[5][2] = {};
  for (int t = 0; t < 8; ++t) {
    int buf = t & 1;
    __syncthreads();
    if (t < 7) {
      int k1 = (t + 1) * 32;
#pragma unroll
      for (int g = 0; g < 5; ++g)
        gload_lds16(wpk + (size_t)(wv * 80 + g * 16 + grow) * 256 + k1 + gc,
                    &As[buf ^ 1][(wv * 80 + g * 16) * 32]);
    }
    bf8 bfr[2];
#pragma unroll
    for (int j = 0; j < 2; ++j)
#pragma unroll
      for (int e = 0; e < 8; ++e) bfr[j][e] = (__bf16)xr[j][e];
    if (t < 7) {
      int k1 = (t + 1) * 32;
#pragma unroll
      for (int j = 0; j < 2; ++j)
#pragma unroll
        for (int e = 0; e < 8; ++e)
          xr[j][e] = xb[(size_t)(k1 + hi4 * 8 + e) * N_ + n0 + j * 16 + fcol];
    }
#pragma unroll
    for (int s = 0; s < 5; ++s) {
      bf8 af = *(const bf8*)&As[buf][(wv * 80 + s * 16 + fcol) * 32 + hi4 * 8];
      acc[s][0] = __builtin_amdgcn_mfma_f32_16x16x32_bf16(af, bfr[0], acc[s][0], 0, 0, 0);
      acc[s][1] = __builtin_amdgcn_mfma_f32_16x16x32_bf16(af, bfr[1], acc[s][1], 0, 0, 0);
    }
  }
  int rq = hi4 * 4;
#pragma unroll
  for (int s = 0; s < 5; ++s)
#pragma unroll
    for (int r = 0; r < 4; ++r) {
      int m = wv * 80 + s * 16 + rq + r;
      float bias = bpk[m];
#pragma unroll
      for (int j = 0; j < 2; ++j) {
        int n = n0 + j * 16 + fcol;
        float val = acc[s][j][r] + bias;
        if (m < 256)
          vbf[((size_t)b * C_ + m) * VP_ + n] = __float2bfloat16(val);
        else
          qkb[((size_t)b * N_ + n) * 64 + (m - 256)] = __float2bfloat16(val);
      }
    }
}

// ---- fused attention v7b: R1 decomposition (512 blocks, 4 waves, no dup) +
// cross-barrier software pipeline. Body t (BUF = t&1, compile-time per unroll):
//   ds_read P(t) from pS[BUF]          (published by barrier of body t-1)
//   S(t+1) = mfma(K(t+1) [regs], Q)    (independent of P(t))
//   prefetch K(t+2) -> other K set
//   PV(t): 8 MFMAs (V(t) regs x P(t))  (independent of S chain)
//   prefetch V(t+2) -> same V set      (after consumption; 2-body distance)
//   exp2(S) -> pack P(t+1) -> pS[BUF^1]; lgkm drain; s_barrier.
// Barrier data is consumed a full body later -> produce/consume decoupled.
#define ATTN_BODY(T, BUF, KC0, KC1, KN0, KN1, VC0, VC1, VC2, VC3)              \
  {                                                                            \
    const __hip_bfloat16* pr_ = &pS[BUF][l31][hi * 8];                         \
    bf8 pf0_ = *(const bf8*)(pr_ + 0);                                         \
    bf8 pf4_ = *(const bf8*)(pr_ + 32 * 88);                                   \
    bf8 pf1_ = *(const bf8*)(pr_ + 16);                                        \
    bf8 pf5_ = *(const bf8*)(pr_ + 32 * 88 + 16);                              \
    bf8 pf2_ = *(const bf8*)(pr_ + 32);                                        \
    bf8 pf6_ = *(const bf8*)(pr_ + 32 * 88 + 32);                              \
    bf8 pf3_ = *(const bf8*)(pr_ + 48);                                        \
    bf8 pf7_ = *(const bf8*)(pr_ + 32 * 88 + 48);                              \
    f16v s_ = {};                                                              \
    if ((T) + 1 < NT_) {                                                       \
      s_ = __builtin_amdgcn_mfma_f32_32x32x16_bf16(KC0, qf0, s_, 0, 0, 0);     \
      s_ = __builtin_amdgcn_mfma_f32_32x32x16_bf16(KC1, qf1, s_, 0, 0, 0);     \
    }                                                                          \
    {                                                                          \
      int tn_ = (T) + 2 < NT_ ? (T) + 2 : NT_ - 1;                             \
      const __hip_bfloat16* kpn_ = kp + (size_t)tn_ * 64 * 64;                 \
      KN0 = *(const bf8*)kpn_;                                                 \
      KN1 = *(const bf8*)(kpn_ + 16);                                          \
    }                                                                          \
    __builtin_amdgcn_s_setprio(1);                                             \
    acc0 = __builtin_amdgcn_mfma_f32_32x32x16_bf16(VC0, pf0_, acc0, 0, 0, 0);  \
    acc1 = __builtin_amdgcn_mfma_f32_32x32x16_bf16(VC0, pf4_, acc1, 0, 0, 0);  \
    acc0 = __builtin_amdgcn_mfma_f32_32x32x16_bf16(VC1, pf1_, acc0, 0, 0, 0);  \
    acc1 = __builtin_amdgcn_mfma_f32_32x32x16_bf16(VC1, pf5_, acc1, 0, 0, 0);  \
    acc0 = __builtin_amdgcn_mfma_f32_32x32x16_bf16(VC2, pf2_, acc0, 0, 0, 0);  \
    acc1 = __builtin_amdgcn_mfma_f32_32x32x16_bf16(VC2, pf6_, acc1, 0, 0, 0);  \
    acc0 = __builtin_amdgcn_mfma_f32_32x32x16_bf16(VC3, pf3_, acc0, 0, 0, 0);  \
    acc1 = __builtin_amdgcn_mfma_f32_32x32x16_bf16(VC3, pf7_, acc1, 0, 0, 0);  \
    __builtin_amdgcn_s_setprio(0);                                             \
    {                                                                          \
      int tn_ = (T) + 2 < NT_ ? (T) + 2 : NT_ - 1;                             \
      const __hip_bfloat16* vpn_ = vR + tn_ * 64;                              \
      VC0 = *(const bf8*)vpn_;                                                 \
      VC1 = *(const bf8*)(vpn_ + 16);                                          \
      VC2 = *(const bf8*)(vpn_ + 32);                                          \
      VC3 = *(const bf8*)(vpn_ + 48);                                          \
    }                                                                          \
    if ((T) + 1 < NT_) {                                                       \
      _Pragma("unroll")                                                        \
      for (int r = 0; r < 16; ++r) s_[r] = __builtin_amdgcn_exp2f(s_[r]);      \
      _Pragma("unroll")                                                        \
      for (int r = 0; r < 16; r += 2) { lp0 += s_[r]; lp1 += s_[r + 1]; }      \
      __hip_bfloat16* pw_ = &pS[(BUF) ^ 1][ws_i * 32 + l31][ws_j * 32 + 4 * hi];\
      _Pragma("unroll")                                                        \
      for (int q = 0; q < 4; ++q) {                                            \
        bf4 tb_;                                                               \
        tb_[0] = (__bf16)s_[4 * q + 0];                                        \
        tb_[1] = (__bf16)s_[4 * q + 1];                                        \
        tb_[2] = (__bf16)s_[4 * q + 2];                                        \
        tb_[3] = (__bf16)s_[4 * q + 3];                                        \
        *(bf4*)(pw_ + 8 * q) = tb_;                                            \
      }                                                                        \
      asm volatile("s_waitcnt lgkmcnt(0)" ::: "memory");                       \
      __builtin_amdgcn_sched_barrier(0);                                       \
      __builtin_amdgcn_s_barrier();                                            \
      __builtin_amdgcn_sched_barrier(0);                                       \
    }                                                                          \
  }

__global__ __launch_bounds__(256, 2) void fused_attn(
    const __hip_bfloat16* __restrict__ qk,   // [b][n][64]: q 0..31, k 32..63
    const __hip_bfloat16* __restrict__ vbf,  // [b][c][VP_]
    const float* __restrict__ x, float* __restrict__ out) {
  __shared__ __attribute__((aligned(16))) __hip_bfloat16 pS[2][64][88];  // 22 KB
  __shared__ float lSp[2][64];
  int tid = threadIdx.x;
  int wv = tid >> 6, lane = tid & 63;
  int l31 = lane & 31, hi = lane >> 5;
  int ws_i = wv >> 1, ws_j = wv & 1;
  // XCD-pinning: b = blk&7 pins batch b's 64 blocks to one XCD's L2.
  int blk = blockIdx.x;
  int b = blk & 7;
  int rest = blk >> 3;
  int c0 = (rest & 1) * 128;
  int i0 = (rest >> 1) * 64;

  const __hip_bfloat16* qkB = qk + (size_t)b * N_ * 64;
  // Q frag (B of S^T): col i = i0 + ws_i*32 + l31, k = h
  const __hip_bfloat16* qp = qkB + (size_t)(i0 + ws_i * 32 + l31) * 64 + hi * 8;
  bf8 qf0 = *(const bf8*)qp;
  bf8 qf1 = *(const bf8*)(qp + 16);
  // K frag (A of S^T): row j = t*64 + ws_j*32 + l31, k = h
  const __hip_bfloat16* kp = qkB + (size_t)(ws_j * 32 + l31) * 64 + 32 + hi * 8;
  // V frag (A of PV): row c = c0 + wv*32 + l31, k = j-local
  const __hip_bfloat16* vR =
      vbf + ((size_t)b * C_ + c0 + wv * 32 + l31) * VP_ + hi * 8;

  // Prologue reg loads: K(0) transient; K(1)->kO; V(0)->vE; V(1)->vO.
  bf8 k00 = *(const bf8*)kp;
  bf8 k01 = *(const bf8*)(kp + 16);
  bf8 kO0 = *(const bf8*)(kp + 64 * 64);
  bf8 kO1 = *(const bf8*)(kp + 64 * 64 + 16);
  bf8 kE0, kE1;
  bf8 vE0 = *(const bf8*)vR;
  bf8 vE1 = *(const bf8*)(vR + 16);
  bf8 vE2 = *(const bf8*)(vR + 32);
  bf8 vE3 = *(const bf8*)(vR + 48);
  bf8 vO0 = *(const bf8*)(vR + 64);
  bf8 vO1 = *(const bf8*)(vR + 64 + 16);
  bf8 vO2 = *(const bf8*)(vR + 64 + 32);
  bf8 vO3 = *(const bf8*)(vR + 64 + 48);

  f16v acc0 = {}, acc1 = {};
  float lp0 = 0.f, lp1 = 0.f;

  // Prologue S(0): exp2, pack, publish P(0) -> pS[0]
  {
    f16v s_ = {};
    s_ = __builtin_amdgcn_mfma_f32_32x32x16_bf16(k00, qf0, s_, 0, 0, 0);
    s_ = __builtin_amdgcn_mfma_f32_32x32x16_bf16(k01, qf1, s_, 0, 0, 0);
#pragma unroll
    for (int r = 0; r < 16; ++r) s_[r] = __builtin_amdgcn_exp2f(s_[r]);
#pragma unroll
    for (int r = 0; r < 16; r += 2) { lp0 += s_[r]; lp1 += s_[r + 1]; }
    __hip_bfloat16* pw_ = &pS[0][ws_i * 32 + l31][ws_j * 32 + 4 * hi];
#pragma unroll
    for (int q = 0; q < 4; ++q) {
      bf4 tb_;
      tb_[0] = (__bf16)s_[4 * q + 0];
      tb_[1] = (__bf16)s_[4 * q + 1];
      tb_[2] = (__bf16)s_[4 * q + 2];
      tb_[3] = (__bf16)s_[4 * q + 3];
      *(bf4*)(pw_ + 8 * q) = tb_;
    }
    asm volatile("s_waitcnt lgkmcnt(0)" ::: "memory");
    __builtin_amdgcn_sched_barrier(0);
    __builtin_amdgcn_s_barrier();
    __builtin_amdgcn_sched_barrier(0);
  }

  for (int tt = 0; tt < NT_; tt += 2) {
    ATTN_BODY(tt,     0, kO0, kO1, kE0, kE1, vE0, vE1, vE2, vE3)
    ATTN_BODY(tt + 1, 1, kE0, kE1, kO0, kO1, vO0, vO1, vO2, vO3)
  }
#undef ATTN_BODY

  // softmax denominator: lane-local sum + hi-half exchange + cross-ws_j via LDS
  float lp = lp0 + lp1;
  lp += __shfl_xor(lp, 32);
  if (lane < 32) lSp[ws_j][ws_i * 32 + l31] = lp;
  __syncthreads();
  float linv0 = 1.0f / (lSp[0][l31] + lSp[1][l31]);
  float linv1 = 1.0f / (lSp[0][32 + l31] + lSp[1][32 + l31]);

  const float* xr = x + (size_t)b * C_ * N_;
  float* op = out + (size_t)b * C_ * N_;
#pragma unroll
  for (int r = 0; r < 16; ++r) {
    int crow = (r & 3) + 8 * (r >> 2) + 4 * hi;
    size_t o = (size_t)(c0 + wv * 32 + crow) * N_ + i0 + l31;
    op[o] = acc0[r] * linv0 + xr[o];
    op[o + 32] = acc1[r] * linv1 + xr[o + 32];
  }
}

extern "C" void kernel_launch(void* const* d_in, const int* in_sizes, int n_in,
                              void* d_out, int out_size, void* d_ws, size_t ws_size,
                              hipStream_t stream) {
  const float* x  = (const float*)d_in[0];
  const float* wq = (const float*)d_in[1];
  const float* bq = (const float*)d_in[2];
  const float* wk = (const float*)d_in[3];
  const float* bk = (const float*)d_in[4];
  const float* wv = (const float*)d_in[5];
  const float* bv = (const float*)d_in[6];
  float* out = (float*)d_out;

  char* ws = (char*)d_ws;
  __hip_bfloat16* qkb = (__hip_bfloat16*)ws;                        // 2 MiB [b][n][64]
  __hip_bfloat16* vbf = (__hip_bfloat16*)(ws + (2u << 20));         // 8.06 MiB [b][c][VP_]
  __hip_bfloat16* wpk = (__hip_bfloat16*)(ws + 10551296u);          // 160 KiB [320][256]
  float*          bpk = (float*)(ws + 10551296u + 163840u);

  pack_kernel<<<dim3(320), 256, 0, stream>>>(wq, wk, wv, bq, bk, bv, wpk, bpk);
  proj_kernel<<<dim3(N_ / 32, B_), 256, 0, stream>>>(x, wpk, bpk, vbf, qkb);
  fused_attn<<<dim3(512), 256, 0, stream>>>(qkb, vbf, x, out);
}